// Round 1
// baseline (215.122 us; speedup 1.0000x reference)
//
#include <hip/hip_runtime.h>

typedef unsigned short u16;
typedef float f32x4 __attribute__((ext_vector_type(4)));
typedef __bf16 bf16x8 __attribute__((ext_vector_type(8)));
typedef unsigned int u32x4 __attribute__((ext_vector_type(4)));
typedef u16 u16x4 __attribute__((ext_vector_type(4)));
typedef u16 u16x8 __attribute__((ext_vector_type(8)));

static __device__ __forceinline__ u16 f2bf(float f) {
  union { float f; unsigned u; } a; a.f = f;
  unsigned u = a.u;
  return (u16)((u + 0x7fffu + ((u >> 16) & 1u)) >> 16);
}

// ---------------- fp32 -> bf16 convert ----------------
__global__ __launch_bounds__(256) void cvt_f32_bf16(const float* __restrict__ in,
                                                    u16* __restrict__ out, int n4) {
  int i = blockIdx.x * 256 + threadIdx.x;
  if (i < n4) {
    f32x4 v = *((const f32x4*)in + i);
    u16x4 o;
    o[0] = f2bf(v[0]); o[1] = f2bf(v[1]); o[2] = f2bf(v[2]); o[3] = f2bf(v[3]);
    *((u16x4*)out + i) = o;
  }
}

// ---------------- GEMM: C[M,N] = A[M,K] * B[N,K]^T (bf16 in, fp32 acc) ----------------
// 128x128 tile, BK=32, 256 threads = 4 waves (2x2), each wave 64x64 via 4x4 16x16x32 MFMA.
template<int OUT_BF16>
__global__ __launch_bounds__(256) void gemm_nt(const u16* __restrict__ A,
                                               const u16* __restrict__ B,
                                               void* __restrict__ Cp,
                                               int M, int N, int K) {
  __shared__ __align__(16) u16 lA[128 * 32];
  __shared__ __align__(16) u16 lB[128 * 32];
  const int tid = threadIdx.x;
  const int lane = tid & 63;
  const int wave = tid >> 6;
  const int wm = wave >> 1, wn = wave & 1;
  const int l15 = lane & 15, lg = lane >> 4;
  const int bm = blockIdx.y * 128, bn = blockIdx.x * 128;

  f32x4 acc[4][4];
#pragma unroll
  for (int i = 0; i < 4; ++i)
#pragma unroll
    for (int j = 0; j < 4; ++j) acc[i][j] = (f32x4){0.f, 0.f, 0.f, 0.f};

  const int c0 = tid, c1 = tid + 256;
  const u16* A0 = A + (size_t)(bm + (c0 >> 2)) * K + (c0 & 3) * 8;
  const u16* A1 = A + (size_t)(bm + (c1 >> 2)) * K + (c1 & 3) * 8;
  const u16* B0 = B + (size_t)(bn + (c0 >> 2)) * K + (c0 & 3) * 8;
  const u16* B1 = B + (size_t)(bn + (c1 >> 2)) * K + (c1 & 3) * 8;

  for (int k0 = 0; k0 < K; k0 += 32) {
    *(u32x4*)&lA[c0 * 8] = *(const u32x4*)(A0 + k0);
    *(u32x4*)&lA[c1 * 8] = *(const u32x4*)(A1 + k0);
    *(u32x4*)&lB[c0 * 8] = *(const u32x4*)(B0 + k0);
    *(u32x4*)&lB[c1 * 8] = *(const u32x4*)(B1 + k0);
    __syncthreads();
    bf16x8 af[4], bfv[4];
#pragma unroll
    for (int mf = 0; mf < 4; ++mf)
      af[mf] = *(const bf16x8*)&lA[(wm * 64 + mf * 16 + l15) * 32 + lg * 8];
#pragma unroll
    for (int nf = 0; nf < 4; ++nf)
      bfv[nf] = *(const bf16x8*)&lB[(wn * 64 + nf * 16 + l15) * 32 + lg * 8];
#pragma unroll
    for (int mf = 0; mf < 4; ++mf)
#pragma unroll
      for (int nf = 0; nf < 4; ++nf)
        acc[mf][nf] = __builtin_amdgcn_mfma_f32_16x16x32_bf16(af[mf], bfv[nf], acc[mf][nf], 0, 0, 0);
    __syncthreads();
  }

#pragma unroll
  for (int mf = 0; mf < 4; ++mf) {
#pragma unroll
    for (int r = 0; r < 4; ++r) {
      const int row = bm + wm * 64 + mf * 16 + lg * 4 + r;
#pragma unroll
      for (int nf = 0; nf < 4; ++nf) {
        const int col = bn + wn * 64 + nf * 16 + l15;
        const float v = acc[mf][nf][r];
        if (OUT_BF16) ((u16*)Cp)[(size_t)row * N + col] = f2bf(v);
        else          ((float*)Cp)[(size_t)row * N + col] = v;
      }
    }
  }
}

// ---------------- transpose V: qkv v-part [b,t,h,d] -> vt[bh][d][t] ----------------
__global__ __launch_bounds__(256) void transpose_v(const u16* __restrict__ qkv,
                                                   u16* __restrict__ vt) {
  constexpr int T = 2048, C3 = 3072, D = 64;
  __shared__ u16 lt[64 * 65];
  const int t0 = blockIdx.x * 64;
  const int bh = blockIdx.y;
  const int b = bh >> 4, h = bh & 15;
  const int tid = threadIdx.x;
#pragma unroll
  for (int it = 0; it < 2; ++it) {
    const int c = tid + it * 256;
    const int tr = c >> 3, d0 = (c & 7) * 8;
    u32x4 v = *(const u32x4*)&qkv[((size_t)b * T + t0 + tr) * C3 + 2048 + h * D + d0];
    const u16* pv = (const u16*)&v;
#pragma unroll
    for (int e = 0; e < 8; ++e) lt[tr * 65 + d0 + e] = pv[e];
  }
  __syncthreads();
#pragma unroll
  for (int it = 0; it < 2; ++it) {
    const int c = tid + it * 256;
    const int d = c >> 3, toff = (c & 7) * 8;
    u16x8 tmp;
#pragma unroll
    for (int e = 0; e < 8; ++e) tmp[e] = lt[(toff + e) * 65 + d];
    *(u16x8*)&vt[((size_t)bh * D + d) * T + t0 + toff] = tmp;
  }
}

// ---------------- flash attention fwd (causal), bf16 MFMA ----------------
// block = (q-tile 64, bh); 4 waves x 16 q-rows; KV tile 64.
__global__ __launch_bounds__(256) void attn_fwd(const u16* __restrict__ qkv,
                                                const u16* __restrict__ vt,
                                                u16* __restrict__ y) {
  constexpr int T = 2048, C = 1024, C3 = 3072, D = 64;
  __shared__ __align__(16) u16 lK[64 * 64];
  __shared__ __align__(16) u16 lV[64 * 64];  // V^T tile: row d, col j (swizzled)
  __shared__ __align__(16) u16 lP[4 * 16 * 64];
  const int tid = threadIdx.x, lane = tid & 63, w = tid >> 6;
  const int l15 = lane & 15, lg = lane >> 4;
  const int qt = blockIdx.x, bh = blockIdx.y;
  const int b = bh >> 4, h = bh & 15;
  const int q0 = qt * 64;

  const size_t qoff = ((size_t)b * T + q0 + w * 16 + l15) * C3 + h * D;
  bf16x8 aq0 = *(const bf16x8*)&qkv[qoff + lg * 8];
  bf16x8 aq1 = *(const bf16x8*)&qkv[qoff + 32 + lg * 8];

  float m_r[4], l_r[4];
  f32x4 o_acc[4];
#pragma unroll
  for (int r = 0; r < 4; ++r) { m_r[r] = -3.0e38f; l_r[r] = 0.f; }
#pragma unroll
  for (int nf = 0; nf < 4; ++nf) o_acc[nf] = (f32x4){0.f, 0.f, 0.f, 0.f};

  for (int kt = 0; kt <= qt; ++kt) {
    const int k0 = kt * 64;
    __syncthreads();
#pragma unroll
    for (int it = 0; it < 2; ++it) {
      const int c = tid + it * 256;
      const int row = c >> 3;
      const int off = (c & 7) * 8;                      // elements
      const int sb = (off * 2) ^ ((row & 7) << 4);      // swizzled byte in row
      *(u32x4*)&lK[(row * 128 + sb) >> 1] =
          *(const u32x4*)&qkv[((size_t)b * T + k0 + row) * C3 + C + h * D + off];
      *(u32x4*)&lV[(row * 128 + sb) >> 1] =
          *(const u32x4*)&vt[((size_t)bh * D + row) * T + k0 + off];
    }
    __syncthreads();

    // S = Q K^T
    f32x4 s[4];
#pragma unroll
    for (int nf = 0; nf < 4; ++nf) s[nf] = (f32x4){0.f, 0.f, 0.f, 0.f};
#pragma unroll
    for (int nf = 0; nf < 4; ++nf) {
      const int row = nf * 16 + l15;
      const int x = (row & 7) << 4;
      bf16x8 bk0 = *(const bf16x8*)&lK[(row * 128 + ((lg * 16) ^ x)) >> 1];
      bf16x8 bk1 = *(const bf16x8*)&lK[(row * 128 + ((64 + lg * 16) ^ x)) >> 1];
      s[nf] = __builtin_amdgcn_mfma_f32_16x16x32_bf16(aq0, bk0, s[nf], 0, 0, 0);
      s[nf] = __builtin_amdgcn_mfma_f32_16x16x32_bf16(aq1, bk1, s[nf], 0, 0, 0);
    }

    // scale + causal mask (only diagonal tile)
    const float scale = 0.125f;
#pragma unroll
    for (int nf = 0; nf < 4; ++nf) {
#pragma unroll
      for (int r = 0; r < 4; ++r) {
        float v = s[nf][r] * scale;
        if (kt == qt) {
          if (nf * 16 + l15 > w * 16 + lg * 4 + r) v = -1e30f;
        }
        s[nf][r] = v;
      }
    }

    // online softmax (rows live in 16-lane groups)
    float p[4][4];
#pragma unroll
    for (int r = 0; r < 4; ++r) {
      float mx = fmaxf(fmaxf(s[0][r], s[1][r]), fmaxf(s[2][r], s[3][r]));
      mx = fmaxf(mx, __shfl_xor(mx, 1));
      mx = fmaxf(mx, __shfl_xor(mx, 2));
      mx = fmaxf(mx, __shfl_xor(mx, 4));
      mx = fmaxf(mx, __shfl_xor(mx, 8));
      const float mnew = fmaxf(m_r[r], mx);
      const float fct = __expf(m_r[r] - mnew);
      float sum = 0.f;
#pragma unroll
      for (int nf = 0; nf < 4; ++nf) {
        const float pv = __expf(s[nf][r] - mnew);
        p[nf][r] = pv;
        sum += pv;
      }
      sum += __shfl_xor(sum, 1);
      sum += __shfl_xor(sum, 2);
      sum += __shfl_xor(sum, 4);
      sum += __shfl_xor(sum, 8);
      l_r[r] = l_r[r] * fct + sum;
      m_r[r] = mnew;
#pragma unroll
      for (int nf = 0; nf < 4; ++nf) o_acc[nf][r] *= fct;
    }

    // P -> LDS (bf16, swizzled), per-wave region
#pragma unroll
    for (int r = 0; r < 4; ++r) {
      const int i = lg * 4 + r;
#pragma unroll
      for (int nf = 0; nf < 4; ++nf) {
        const int j = nf * 16 + l15;
        lP[(w * 2048 + i * 128 + ((j * 2) ^ ((i & 7) << 4))) >> 1] = f2bf(p[nf][r]);
      }
    }
    __syncthreads();

    // O += P V
#pragma unroll
    for (int sj = 0; sj < 2; ++sj) {
      bf16x8 ap = *(const bf16x8*)&lP[(w * 2048 + l15 * 128 + ((sj * 64 + lg * 16) ^ ((l15 & 7) << 4))) >> 1];
#pragma unroll
      for (int nf = 0; nf < 4; ++nf) {
        const int d = nf * 16 + l15;
        bf16x8 bv = *(const bf16x8*)&lV[(d * 128 + ((sj * 64 + lg * 16) ^ ((d & 7) << 4))) >> 1];
        o_acc[nf] = __builtin_amdgcn_mfma_f32_16x16x32_bf16(ap, bv, o_acc[nf], 0, 0, 0);
      }
    }
  }

  // epilogue: y[b, t, h*D + d] bf16
#pragma unroll
  for (int nf = 0; nf < 4; ++nf) {
#pragma unroll
    for (int r = 0; r < 4; ++r) {
      const int row = q0 + w * 16 + lg * 4 + r;
      const int col = h * D + nf * 16 + l15;
      y[((size_t)b * T + row) * C + col] = f2bf(o_acc[nf][r] / l_r[r]);
    }
  }
}

extern "C" void kernel_launch(void* const* d_in, const int* in_sizes, int n_in,
                              void* d_out, int out_size, void* d_ws, size_t ws_size,
                              hipStream_t stream) {
  const float* x = (const float*)d_in[0];
  const float* Wqkv = (const float*)d_in[1];
  const float* Wproj = (const float*)d_in[2];
  float* out = (float*)d_out;

  constexpr int B = 2, T = 2048, C = 1024, C3 = 3072, H = 16, D = 64;
  constexpr int M = B * T;  // 4096

  u16* xb = (u16*)d_ws;                       // M*C
  u16* wqkvb = xb + (size_t)M * C;            // C3*C
  u16* wprojb = wqkvb + (size_t)C3 * C;       // C*C
  u16* qkvb = wprojb + (size_t)C * C;         // M*C3
  u16* vtb = qkvb + (size_t)M * C3;           // B*H*D*T = M*C
  u16* yb = vtb + (size_t)M * C;              // M*C

  cvt_f32_bf16<<<dim3((M * C) / 4 / 256), 256, 0, stream>>>(x, xb, (M * C) / 4);
  cvt_f32_bf16<<<dim3((C3 * C) / 4 / 256), 256, 0, stream>>>(Wqkv, wqkvb, (C3 * C) / 4);
  cvt_f32_bf16<<<dim3((C * C) / 4 / 256), 256, 0, stream>>>(Wproj, wprojb, (C * C) / 4);

  gemm_nt<1><<<dim3(C3 / 128, M / 128), 256, 0, stream>>>(xb, wqkvb, qkvb, M, C3, C);
  transpose_v<<<dim3(T / 64, B * H), 256, 0, stream>>>(qkvb, vtb);
  attn_fwd<<<dim3(T / 64, B * H), 256, 0, stream>>>(qkvb, vtb, yb);
  gemm_nt<0><<<dim3(C / 128, M / 128), 256, 0, stream>>>(yb, wprojb, out, M, C, C);
}

// Round 3
// 137.535 us; speedup vs baseline: 1.5641x; 1.5641x over previous
//
#include <hip/hip_runtime.h>

typedef unsigned short u16;
typedef float f32x4 __attribute__((ext_vector_type(4)));
typedef __bf16 bf16x8 __attribute__((ext_vector_type(8)));
typedef unsigned int u32x4 __attribute__((ext_vector_type(4)));
typedef u16 u16x4 __attribute__((ext_vector_type(4)));
typedef u16 u16x8 __attribute__((ext_vector_type(8)));

static __device__ __forceinline__ u16 f2bf(float f) {
  union { float f; unsigned u; } a; a.f = f;
  unsigned u = a.u;
  return (u16)((u + 0x7fffu + ((u >> 16) & 1u)) >> 16);
}

static __device__ __forceinline__ void gload_lds16(const void* g, void* l) {
  __builtin_amdgcn_global_load_lds(
      (const __attribute__((address_space(1))) unsigned int*)g,
      (__attribute__((address_space(3))) unsigned int*)l, 16, 0, 0);
}

// ---------------- fp32 -> bf16 convert ----------------
__global__ __launch_bounds__(256) void cvt_f32_bf16(const float* __restrict__ in,
                                                    u16* __restrict__ out, int n4) {
  int i = blockIdx.x * 256 + threadIdx.x;
  if (i < n4) {
    f32x4 v = *((const f32x4*)in + i);
    u16x4 o;
    o[0] = f2bf(v[0]); o[1] = f2bf(v[1]); o[2] = f2bf(v[2]); o[3] = f2bf(v[3]);
    *((u16x4*)out + i) = o;
  }
}

// ---------------- GEMM: C[M,N] = A[M,K] * B[N,K]^T (bf16 in, fp32 acc) ----------------
// 128x128 tile, BK=64, 256 threads = 4 waves (2x2). global_load_lds staging with
// pre-swizzled source (g ^= row&7) + XOR-swizzled ds_read (both-sides swizzle).
template<int OUT_BF16>
__global__ __launch_bounds__(256) void gemm_nt(const u16* __restrict__ A,
                                               const u16* __restrict__ B,
                                               void* __restrict__ Cp,
                                               int M, int N, int K) {
  __shared__ __align__(16) u16 lA[128 * 64];
  __shared__ __align__(16) u16 lB[128 * 64];
  const int tid = threadIdx.x;
  const int lane = tid & 63;
  const int wave = tid >> 6;
  const int wm = wave >> 1, wn = wave & 1;
  const int l15 = lane & 15, lg = lane >> 4;
  const int bm = blockIdx.y * 128, bn = blockIdx.x * 128;

  f32x4 acc[4][4];
#pragma unroll
  for (int i = 0; i < 4; ++i)
#pragma unroll
    for (int j = 0; j < 4; ++j) acc[i][j] = (f32x4){0.f, 0.f, 0.f, 0.f};

  const u16* Ag[4];
  const u16* Bg[4];
#pragma unroll
  for (int it = 0; it < 4; ++it) {
    const int s = it * 256 + tid;
    const int row = s >> 3, g = s & 7;
    const int gsw = g ^ (row & 7);  // inverse swizzle on global source
    Ag[it] = A + (size_t)(bm + row) * K + gsw * 8;
    Bg[it] = B + (size_t)(bn + row) * K + gsw * 8;
  }

  for (int k0 = 0; k0 < K; k0 += 64) {
#pragma unroll
    for (int it = 0; it < 4; ++it) {
      gload_lds16(Ag[it] + k0, (u16*)lA + (size_t)(it * 256 + tid) * 8);
      gload_lds16(Bg[it] + k0, (u16*)lB + (size_t)(it * 256 + tid) * 8);
    }
    __syncthreads();
#pragma unroll
    for (int kk = 0; kk < 2; ++kk) {
      bf16x8 af[4], bfv[4];
#pragma unroll
      for (int mf = 0; mf < 4; ++mf) {
        const int row = wm * 64 + mf * 16 + l15;
        af[mf] = *(const bf16x8*)((const char*)lA + row * 128 +
                                  ((kk * 64 + lg * 16) ^ ((row & 7) << 4)));
      }
#pragma unroll
      for (int nf = 0; nf < 4; ++nf) {
        const int row = wn * 64 + nf * 16 + l15;
        bfv[nf] = *(const bf16x8*)((const char*)lB + row * 128 +
                                   ((kk * 64 + lg * 16) ^ ((row & 7) << 4)));
      }
#pragma unroll
      for (int mf = 0; mf < 4; ++mf)
#pragma unroll
        for (int nf = 0; nf < 4; ++nf)
          acc[mf][nf] = __builtin_amdgcn_mfma_f32_16x16x32_bf16(af[mf], bfv[nf], acc[mf][nf], 0, 0, 0);
    }
    __syncthreads();
  }

#pragma unroll
  for (int mf = 0; mf < 4; ++mf) {
#pragma unroll
    for (int r = 0; r < 4; ++r) {
      const int row = bm + wm * 64 + mf * 16 + lg * 4 + r;
#pragma unroll
      for (int nf = 0; nf < 4; ++nf) {
        const int col = bn + wn * 64 + nf * 16 + l15;
        const float v = acc[mf][nf][r];
        if (OUT_BF16) ((u16*)Cp)[(size_t)row * N + col] = f2bf(v);
        else          ((float*)Cp)[(size_t)row * N + col] = v;
      }
    }
  }
}

// ---------------- transpose V: qkv v-part [b,t,h,d] -> vt[bh][d][t] ----------------
__global__ __launch_bounds__(256) void transpose_v(const u16* __restrict__ qkv,
                                                   u16* __restrict__ vt) {
  constexpr int T = 2048, C3 = 3072, D = 64;
  __shared__ u16 lt[64 * 65];
  const int t0 = blockIdx.x * 64;
  const int bh = blockIdx.y;
  const int b = bh >> 4, h = bh & 15;
  const int tid = threadIdx.x;
#pragma unroll
  for (int it = 0; it < 2; ++it) {
    const int c = tid + it * 256;
    const int tr = c >> 3, d0 = (c & 7) * 8;
    u32x4 v = *(const u32x4*)&qkv[((size_t)b * T + t0 + tr) * C3 + 2048 + h * D + d0];
    const u16* pv = (const u16*)&v;
#pragma unroll
    for (int e = 0; e < 8; ++e) lt[tr * 65 + d0 + e] = pv[e];
  }
  __syncthreads();
#pragma unroll
  for (int it = 0; it < 2; ++it) {
    const int c = tid + it * 256;
    const int d = c >> 3, toff = (c & 7) * 8;
    u16x8 tmp;
#pragma unroll
    for (int e = 0; e < 8; ++e) tmp[e] = lt[(toff + e) * 65 + d];
    *(u16x8*)&vt[((size_t)bh * D + d) * T + t0 + toff] = tmp;
  }
}

// ---------------- flash attention fwd (causal), bf16 MFMA ----------------
// Balanced pairing: block (x,bh) processes q-tiles {x, 31-x} -> 33 kv-iters/block.
// 4 waves x 16 q-rows; KV tile 64; reg-prefetch (T14) of next K/V tile; 2 barriers/iter.
__global__ __launch_bounds__(256) void attn_fwd(const u16* __restrict__ qkv,
                                                const u16* __restrict__ vt,
                                                u16* __restrict__ y) {
  constexpr int T = 2048, C = 1024, C3 = 3072, D = 64, NQ = 32;
  __shared__ __align__(16) u16 lK[64 * 64];
  __shared__ __align__(16) u16 lV[64 * 64];  // V^T tile: row d, col j (swizzled)
  __shared__ __align__(16) u16 lP[4 * 16 * 64];
  const int tid = threadIdx.x, lane = tid & 63, w = tid >> 6;
  const int l15 = lane & 15, lg = lane >> 4;
  const int bh = blockIdx.y;
  const int b = bh >> 4, h = bh & 15;

  // staging mapping (two 16B chunks per thread per tile)
  const int r0 = tid >> 3, off0 = (tid & 7) * 8;
  const int r1 = (tid + 256) >> 3, off1 = off0;
  const int sb0 = (off0 * 2) ^ ((r0 & 7) << 4);
  const int sb1 = (off1 * 2) ^ ((r1 & 7) << 4);
  const u16* Kbase = qkv + (size_t)b * T * C3 + C + h * D;
  const u16* Vbase = vt + (size_t)bh * D * T;

  const float qscale = 0.125f * 1.44269504088896f;  // scale * log2(e)

#pragma unroll 1
  for (int qi = 0; qi < 2; ++qi) {
    const int qt = (qi == 0) ? (int)blockIdx.x : (NQ - 1 - (int)blockIdx.x);
    const int q0 = qt * 64;

    const size_t qoff = ((size_t)b * T + q0 + w * 16 + l15) * C3 + h * D;
    const bf16x8 aq0 = *(const bf16x8*)&qkv[qoff + lg * 8];
    const bf16x8 aq1 = *(const bf16x8*)&qkv[qoff + 32 + lg * 8];

    float m_r[4], l_r[4];
    f32x4 o_acc[4];
#pragma unroll
    for (int r = 0; r < 4; ++r) { m_r[r] = -1.0e30f; l_r[r] = 0.f; }
#pragma unroll
    for (int nf = 0; nf < 4; ++nf) o_acc[nf] = (f32x4){0.f, 0.f, 0.f, 0.f};

    // prologue: prefetch tile 0 into regs
    u32x4 rk0 = *(const u32x4*)(Kbase + (size_t)r0 * C3 + off0);
    u32x4 rk1 = *(const u32x4*)(Kbase + (size_t)r1 * C3 + off1);
    u32x4 rv0 = *(const u32x4*)(Vbase + (size_t)r0 * T + off0);
    u32x4 rv1 = *(const u32x4*)(Vbase + (size_t)r1 * T + off1);

    for (int kt = 0; kt <= qt; ++kt) {
      __syncthreads();  // prev iteration's LDS reads complete
      *(u32x4*)&lK[(r0 * 128 + sb0) >> 1] = rk0;
      *(u32x4*)&lK[(r1 * 128 + sb1) >> 1] = rk1;
      *(u32x4*)&lV[(r0 * 128 + sb0) >> 1] = rv0;
      *(u32x4*)&lV[(r1 * 128 + sb1) >> 1] = rv1;
      if (kt < qt) {  // prefetch next tile (overlaps with compute below)
        const int kn = (kt + 1) * 64;
        rk0 = *(const u32x4*)(Kbase + (size_t)(kn + r0) * C3 + off0);
        rk1 = *(const u32x4*)(Kbase + (size_t)(kn + r1) * C3 + off1);
        rv0 = *(const u32x4*)(Vbase + (size_t)r0 * T + kn + off0);
        rv1 = *(const u32x4*)(Vbase + (size_t)r1 * T + kn + off1);
      }
      __syncthreads();  // LDS tile ready

      // S = Q K^T  (pre-scaled into log2 domain)
      f32x4 s[4];
#pragma unroll
      for (int nf = 0; nf < 4; ++nf) s[nf] = (f32x4){0.f, 0.f, 0.f, 0.f};
#pragma unroll
      for (int nf = 0; nf < 4; ++nf) {
        const int row = nf * 16 + l15;
        const int x = (row & 7) << 4;
        bf16x8 bk0 = *(const bf16x8*)&lK[(row * 128 + ((lg * 16) ^ x)) >> 1];
        bf16x8 bk1 = *(const bf16x8*)&lK[(row * 128 + ((64 + lg * 16) ^ x)) >> 1];
        s[nf] = __builtin_amdgcn_mfma_f32_16x16x32_bf16(aq0, bk0, s[nf], 0, 0, 0);
        s[nf] = __builtin_amdgcn_mfma_f32_16x16x32_bf16(aq1, bk1, s[nf], 0, 0, 0);
      }

#pragma unroll
      for (int nf = 0; nf < 4; ++nf) {
#pragma unroll
        for (int r = 0; r < 4; ++r) {
          float v = s[nf][r] * qscale;
          if (kt == qt) {
            if (nf * 16 + l15 > w * 16 + lg * 4 + r) v = -1.0e30f;
          }
          s[nf][r] = v;
        }
      }

      // online softmax (rows live in 16-lane groups), base-2 domain
      float p[4][4];
#pragma unroll
      for (int r = 0; r < 4; ++r) {
        float mx = fmaxf(fmaxf(s[0][r], s[1][r]), fmaxf(s[2][r], s[3][r]));
        mx = fmaxf(mx, __shfl_xor(mx, 1));
        mx = fmaxf(mx, __shfl_xor(mx, 2));
        mx = fmaxf(mx, __shfl_xor(mx, 4));
        mx = fmaxf(mx, __shfl_xor(mx, 8));
        const float mnew = fmaxf(m_r[r], mx);
        const float fct = __builtin_amdgcn_exp2f(m_r[r] - mnew);
        float sum = 0.f;
#pragma unroll
        for (int nf = 0; nf < 4; ++nf) {
          const float pv = __builtin_amdgcn_exp2f(s[nf][r] - mnew);
          p[nf][r] = pv;
          sum += pv;
        }
        sum += __shfl_xor(sum, 1);
        sum += __shfl_xor(sum, 2);
        sum += __shfl_xor(sum, 4);
        sum += __shfl_xor(sum, 8);
        l_r[r] = l_r[r] * fct + sum;
        m_r[r] = mnew;
#pragma unroll
        for (int nf = 0; nf < 4; ++nf) o_acc[nf][r] *= fct;
      }

      // P -> per-wave LDS region (bf16, swizzled). No barrier needed: same-wave RAW,
      // DS pipe is in-order per wave.
#pragma unroll
      for (int r = 0; r < 4; ++r) {
        const int i = lg * 4 + r;
#pragma unroll
        for (int nf = 0; nf < 4; ++nf) {
          const int j = nf * 16 + l15;
          lP[(w * 2048 + i * 128 + ((j * 2) ^ ((i & 7) << 4))) >> 1] = f2bf(p[nf][r]);
        }
      }

      // O += P V
#pragma unroll
      for (int sj = 0; sj < 2; ++sj) {
        bf16x8 ap = *(const bf16x8*)&lP[(w * 2048 + l15 * 128 + ((sj * 64 + lg * 16) ^ ((l15 & 7) << 4))) >> 1];
#pragma unroll
        for (int nf = 0; nf < 4; ++nf) {
          const int d = nf * 16 + l15;
          bf16x8 bv = *(const bf16x8*)&lV[(d * 128 + ((sj * 64 + lg * 16) ^ ((d & 7) << 4))) >> 1];
          o_acc[nf] = __builtin_amdgcn_mfma_f32_16x16x32_bf16(ap, bv, o_acc[nf], 0, 0, 0);
        }
      }
    }

    // epilogue: y[b, t, h*D + d] bf16
#pragma unroll
    for (int nf = 0; nf < 4; ++nf) {
#pragma unroll
      for (int r = 0; r < 4; ++r) {
        const int row = q0 + w * 16 + lg * 4 + r;
        const int col = h * D + nf * 16 + l15;
        y[((size_t)b * T + row) * C + col] = f2bf(o_acc[nf][r] / l_r[r]);
      }
    }
  }
}

extern "C" void kernel_launch(void* const* d_in, const int* in_sizes, int n_in,
                              void* d_out, int out_size, void* d_ws, size_t ws_size,
                              hipStream_t stream) {
  const float* x = (const float*)d_in[0];
  const float* Wqkv = (const float*)d_in[1];
  const float* Wproj = (const float*)d_in[2];
  float* out = (float*)d_out;

  constexpr int B = 2, T = 2048, C = 1024, C3 = 3072, H = 16, D = 64;
  constexpr int M = B * T;  // 4096

  u16* xb = (u16*)d_ws;                       // M*C
  u16* wqkvb = xb + (size_t)M * C;            // C3*C
  u16* wprojb = wqkvb + (size_t)C3 * C;       // C*C
  u16* qkvb = wprojb + (size_t)C * C;         // M*C3
  u16* vtb = qkvb + (size_t)M * C3;           // B*H*D*T = M*C
  u16* yb = vtb + (size_t)M * C;              // M*C

  cvt_f32_bf16<<<dim3((M * C) / 4 / 256), 256, 0, stream>>>(x, xb, (M * C) / 4);
  cvt_f32_bf16<<<dim3((C3 * C) / 4 / 256), 256, 0, stream>>>(Wqkv, wqkvb, (C3 * C) / 4);
  cvt_f32_bf16<<<dim3((C * C) / 4 / 256), 256, 0, stream>>>(Wproj, wprojb, (C * C) / 4);

  gemm_nt<1><<<dim3(C3 / 128, M / 128), 256, 0, stream>>>(xb, wqkvb, qkvb, M, C3, C);
  transpose_v<<<dim3(T / 64, B * H), 256, 0, stream>>>(qkvb, vtb);
  attn_fwd<<<dim3(T / 64 / 2, B * H), 256, 0, stream>>>(qkvb, vtb, yb);
  gemm_nt<0><<<dim3(C / 128, M / 128), 256, 0, stream>>>(yb, wprojb, out, M, C, C);
}